// Round 6
// baseline (68.935 us; speedup 1.0000x reference)
//
#include <hip/hip_runtime.h>

#define B_  2048
#define I_  256
#define H_  512
#define D_  768
#define K_  32

typedef unsigned short ushort_t;
typedef unsigned int uint_t;
typedef __attribute__((ext_vector_type(8))) __bf16 bf16x8;
typedef __attribute__((ext_vector_type(4))) float f32x4;

__device__ __forceinline__ ushort_t f2bf(float f) {
  uint_t u = __float_as_uint(f);
  u += 0x7fffu + ((u >> 16) & 1u);   // RNE
  return (ushort_t)(u >> 16);
}
__device__ __forceinline__ float fast_sigmoid(float x) {
  return 1.f / (1.f + __expf(-x));
}
__device__ __forceinline__ float fast_tanh(float x) {
  float t = __expf(2.f * fabsf(x));          // overflow -> inf -> r = 1
  float r = 1.f - 2.f / (t + 1.f);
  return copysignf(r, x);
}
__device__ __forceinline__ void gload16(const void* g, void* l) {
  __builtin_amdgcn_global_load_lds(
      (const __attribute__((address_space(1))) void*)g,
      (__attribute__((address_space(3))) void*)l, 16, 0, 0);
}

// ---- prep kernel: blocks 0..1535 transpose Wc -> wcT bf16;
//      blocks 1536..2303 run the per-feature KAN MLP (phase 1), uT[g][b][d] bf16 ----
__global__ __launch_bounds__(256) void kan_prep(
    const float* __restrict__ x, const float* __restrict__ hp,
    const float* __restrict__ W1, const float* __restrict__ b1,
    const float* __restrict__ W2, const float* __restrict__ b2,
    const float* __restrict__ Wc,
    ushort_t* __restrict__ wcT, ushort_t* __restrict__ uT) {
  __shared__ float ttile[32][33];
  int bid = blockIdx.x;
  if (bid < 1536) {
    int tx = threadIdx.x & 31, ty = threadIdx.x >> 5;
    int g = bid / 384;
    int rem = bid % 384;
    int d0 = (rem / 16) * 32;
    int h0 = (rem % 16) * 32;
#pragma unroll
    for (int i = 0; i < 4; ++i) {
      int r = ty + i * 8;
      ttile[r][tx] = Wc[((size_t)g * D_ + d0 + r) * H_ + h0 + tx];
    }
    __syncthreads();
#pragma unroll
    for (int i = 0; i < 4; ++i) {
      int r = ty + i * 8;                     // h index
      wcT[((size_t)g * H_ + h0 + r) * D_ + d0 + tx] = f2bf(ttile[tx][r]);
    }
  } else {
    int p = bid - 1536;
    int combo = p >> 6;                // 0..11
    int bc = p & 63;
    int g = combo & 3;
    int dc = combo >> 2;               // 0: x[:,0:256], 1: hp[:,0:256], 2: hp[:,256:512]
    int t = threadIdx.x;
    int d = dc * 256 + t;

    f32x4 w1v[8], bbv[8], w2v[8];
    const float* W1p = W1 + ((size_t)g * D_ + d) * K_;
    const float* b1p = b1 + ((size_t)g * D_ + d) * K_;
    const float* W2p = W2 + ((size_t)g * D_ + d) * K_;
#pragma unroll
    for (int q = 0; q < 8; ++q) {
      w1v[q] = *(const f32x4*)(W1p + q * 4);
      bbv[q] = *(const f32x4*)(b1p + q * 4);
      w2v[q] = *(const f32x4*)(W2p + q * 4);
    }
    float bias = b2[(size_t)g * D_ + d];

    const float* src = (dc == 0) ? (x + t) : (hp + ((dc == 1) ? t : t + 256));
    int stride = (dc == 0) ? I_ : H_;
    int b0 = bc * 32;

#pragma unroll
    for (int bb8 = 0; bb8 < 32; bb8 += 8) {
      float cv[8], acc[8];
#pragma unroll
      for (int j = 0; j < 8; ++j) {
        cv[j] = src[(size_t)(b0 + bb8 + j) * stride];
        acc[j] = bias;
      }
#pragma unroll
      for (int q = 0; q < 8; ++q)
#pragma unroll
        for (int e = 0; e < 4; ++e) {
          float w1 = w1v[q][e], bbk = bbv[q][e], w2 = w2v[q][e];
#pragma unroll
          for (int j = 0; j < 8; ++j) {
            float h = fmaxf(fmaf(cv[j], w1, bbk), 0.f);
            acc[j] = fmaf(h, w2, acc[j]);
          }
        }
#pragma unroll
      for (int j = 0; j < 8; ++j)
        uT[((size_t)g * B_ + b0 + bb8 + j) * D_ + d] = f2bf(acc[j]);
    }
  }
}

// ---- phase 2 v6: 128(b) x 128(h) x 4 gates per block, 16 waves (1024 thr),
//      2-buffer global_load_lds pipeline, staged bytes 288MB -> 96MB,
//      4-pass LDS gate exchange + fused LSTM epilogue ----
#define TBM 128
#define THN 128
#define BK2 32
#define NT2 (D_ / BK2)               // 24
#define AREG 32768                   // A region bytes per buffer
#define BUF2 65536                   // per-buffer total (A 32K + B 32K)

__global__ __launch_bounds__(1024) void kan_phase2(
    const ushort_t* __restrict__ uT, const ushort_t* __restrict__ wcT,
    const float* __restrict__ bc, const float* __restrict__ cprev,
    float* __restrict__ out) {
  __shared__ __align__(16) char smem[2 * BUF2];       // 131072 B
  const int b0 = blockIdx.x * TBM;
  const int h0 = blockIdx.y * THN;
  const int t = threadIdx.x;
  const int w = t >> 6;
  const int l = t & 63;
  const int g = w >> 2, mh = (w >> 1) & 1, nh = w & 1;
  const int frow = l & 15, c0 = l >> 4;

  // ---- staging: thread t handles slots t and t+1024 (slot = 16B chunk) ----
  // slot s: row64 = s>>2 (gate*128 + r), chunk c = s&3; LDS linear, global pre-swizzled
  const ushort_t* asrc[2];
  const ushort_t* bsrc[2];
  int aLds[2], bLds[2];
#pragma unroll
  for (int i = 0; i < 2; ++i) {
    int s = t + i * 1024;
    int row = s >> 2, c = s & 3;
    int gg = row >> 7, r = row & 127;
    int cg = c ^ ((r ^ (r >> 2)) & 3);
    asrc[i] = uT + ((size_t)gg * B_ + b0 + r) * D_ + cg * 8;
    bsrc[i] = wcT + ((size_t)gg * H_ + h0 + r) * D_ + cg * 8;
    aLds[i] = s * 16;
    bLds[i] = AREG + s * 16;
  }

  // ---- compute-side LDS offsets (read swizzle = same involution) ----
  const int key = (frow ^ (frow >> 2)) & 3;
  const int cx = ((c0 ^ key) << 4);
  int aoff[4], boff[4];
#pragma unroll
  for (int m = 0; m < 4; ++m)
    aoff[m] = ((g * 128 + mh * 64 + m * 16 + frow) << 6) + cx;
#pragma unroll
  for (int n = 0; n < 4; ++n)
    boff[n] = AREG + ((g * 128 + nh * 64 + n * 16 + frow) << 6) + cx;

  // ---- accumulators, bias folded in (C col = lane&15) ----
  f32x4 acc[4][4];
#pragma unroll
  for (int n = 0; n < 4; ++n) {
    float bv = bc[(size_t)g * H_ + h0 + nh * 64 + n * 16 + frow];
#pragma unroll
    for (int m = 0; m < 4; ++m) acc[m][n] = (f32x4){bv, bv, bv, bv};
  }

  auto stage = [&](int bufoff, int ke) {
#pragma unroll
    for (int i = 0; i < 2; ++i) gload16(asrc[i] + ke, smem + bufoff + aLds[i]);
#pragma unroll
    for (int i = 0; i < 2; ++i) gload16(bsrc[i] + ke, smem + bufoff + bLds[i]);
  };
  auto compute = [&](const char* bb) {
    bf16x8 af[4], bf[4];
#pragma unroll
    for (int m = 0; m < 4; ++m) af[m] = *(const bf16x8*)(bb + aoff[m]);
#pragma unroll
    for (int n = 0; n < 4; ++n) bf[n] = *(const bf16x8*)(bb + boff[n]);
    __builtin_amdgcn_s_setprio(1);
#pragma unroll
    for (int m = 0; m < 4; ++m)
#pragma unroll
      for (int n = 0; n < 4; ++n)
        acc[m][n] = __builtin_amdgcn_mfma_f32_16x16x32_bf16(af[m], bf[n], acc[m][n], 0, 0, 0);
    __builtin_amdgcn_s_setprio(0);
  };

  stage(0, 0);
  int buf = 0;
  for (int s = 0; s < NT2; ++s) {
    asm volatile("s_waitcnt vmcnt(0)" ::: "memory");   // own stage(s) complete
    __builtin_amdgcn_s_barrier();                      // all waves' staging done
    if (s + 1 < NT2) stage((buf ^ 1) * BUF2, (s + 1) * BK2);
    compute(smem + buf * BUF2);
    buf ^= 1;
  }
  __syncthreads();                     // all MFMA reads done before gf overlay

  // ---- epilogue: 4 passes over (mh,nh) sub-tiles; gf [4][64][68] f32 (70KB) ----
  float* gf = (float*)smem;
#pragma unroll 1
  for (int q = 0; q < 4; ++q) {
    if ((w & 3) == q) {                // waves of this (mh,nh) quadrant, all gates
#pragma unroll
      for (int m = 0; m < 4; ++m)
#pragma unroll
        for (int n = 0; n < 4; ++n)
#pragma unroll
          for (int e = 0; e < 4; ++e) {
            int row = m * 16 + c0 * 4 + e;
            int col = n * 16 + frow;
            gf[((size_t)g * 64 + row) * 68 + col] = acc[m][n][e];
          }
    }
    __syncthreads();
    {
      int row = t >> 4;                // 0..63
      int ch = t & 15;
      int b = b0 + (q >> 1) * 64 + row;
      int hc = h0 + (q & 1) * 64 + ch * 4;
      f32x4 g0 = *(const f32x4*)&gf[((size_t)0 * 64 + row) * 68 + ch * 4];
      f32x4 g1 = *(const f32x4*)&gf[((size_t)1 * 64 + row) * 68 + ch * 4];
      f32x4 g2 = *(const f32x4*)&gf[((size_t)2 * 64 + row) * 68 + ch * 4];
      f32x4 g3 = *(const f32x4*)&gf[((size_t)3 * 64 + row) * 68 + ch * 4];
      f32x4 cp = *(const f32x4*)&cprev[(size_t)b * H_ + hc];
      f32x4 hv, cv;
#pragma unroll
      for (int e = 0; e < 4; ++e) {
        float ft = fast_sigmoid(g0[e]);
        float it = fast_sigmoid(g1[e]);
        float ot = fast_sigmoid(g2[e]);
        float tc = fast_tanh(g3[e]);
        float cn = ft * cp[e] + it * tc;
        cv[e] = cn;
        hv[e] = ot * fast_tanh(cn);
      }
      *(f32x4*)&out[(size_t)b * H_ + hc] = hv;
      *(f32x4*)&out[(size_t)B_ * H_ + (size_t)b * H_ + hc] = cv;
    }
    __syncthreads();
  }
}

extern "C" void kernel_launch(void* const* d_in, const int* in_sizes, int n_in,
                              void* d_out, int out_size, void* d_ws, size_t ws_size,
                              hipStream_t stream) {
  const float* x  = (const float*)d_in[0];
  const float* hp = (const float*)d_in[1];
  const float* cp = (const float*)d_in[2];
  const float* W1 = (const float*)d_in[3];
  const float* b1 = (const float*)d_in[4];
  const float* W2 = (const float*)d_in[5];
  const float* b2 = (const float*)d_in[6];
  const float* Wc = (const float*)d_in[7];
  const float* bc = (const float*)d_in[8];
  float* out = (float*)d_out;

  // workspace layout
  ushort_t* wcT = (ushort_t*)d_ws;                  // 4*512*768 bf16
  ushort_t* uT  = wcT + (size_t)4 * H_ * D_;        // 4*2048*768 bf16

  kan_prep<<<2304, 256, 0, stream>>>(x, hp, W1, b1, W2, b2, Wc, wcT, uT);
  kan_phase2<<<dim3(B_ / TBM, H_ / THN), 1024, 0, stream>>>(uT, wcT, bc, cp, out);
}

// Round 7
// 47.169 us; speedup vs baseline: 1.4615x; 1.4615x over previous
//
#include <hip/hip_runtime.h>

#define B_  2048
#define I_  256
#define H_  512
#define D_  768
#define K_  32

typedef unsigned short ushort_t;
typedef unsigned int uint_t;
typedef __attribute__((ext_vector_type(8))) __bf16 bf16x8;
typedef __attribute__((ext_vector_type(4))) float f32x4;

__device__ __forceinline__ ushort_t f2bf(float f) {
  uint_t u = __float_as_uint(f);
  u += 0x7fffu + ((u >> 16) & 1u);   // RNE
  return (ushort_t)(u >> 16);
}
__device__ __forceinline__ float fast_sigmoid(float x) {
  return 1.f / (1.f + __expf(-x));
}
__device__ __forceinline__ float fast_tanh(float x) {
  float t = __expf(2.f * fabsf(x));          // overflow -> inf -> r = 1
  float r = 1.f - 2.f / (t + 1.f);
  return copysignf(r, x);
}
__device__ __forceinline__ void gload16(const void* g, void* l) {
  __builtin_amdgcn_global_load_lds(
      (const __attribute__((address_space(1))) void*)g,
      (__attribute__((address_space(3))) void*)l, 16, 0, 0);
}

// ---- prep kernel: blocks 0..1535 transpose Wc -> wcT bf16;
//      blocks 1536..2303 run the per-feature KAN MLP (phase 1), uT[g][b][d] bf16 ----
__global__ __launch_bounds__(256) void kan_prep(
    const float* __restrict__ x, const float* __restrict__ hp,
    const float* __restrict__ W1, const float* __restrict__ b1,
    const float* __restrict__ W2, const float* __restrict__ b2,
    const float* __restrict__ Wc,
    ushort_t* __restrict__ wcT, ushort_t* __restrict__ uT) {
  __shared__ float ttile[32][33];
  int bid = blockIdx.x;
  if (bid < 1536) {
    int tx = threadIdx.x & 31, ty = threadIdx.x >> 5;
    int g = bid / 384;
    int rem = bid % 384;
    int d0 = (rem / 16) * 32;
    int h0 = (rem % 16) * 32;
#pragma unroll
    for (int i = 0; i < 4; ++i) {
      int r = ty + i * 8;
      ttile[r][tx] = Wc[((size_t)g * D_ + d0 + r) * H_ + h0 + tx];
    }
    __syncthreads();
#pragma unroll
    for (int i = 0; i < 4; ++i) {
      int r = ty + i * 8;                     // h index
      wcT[((size_t)g * H_ + h0 + r) * D_ + d0 + tx] = f2bf(ttile[tx][r]);
    }
  } else {
    int p = bid - 1536;
    int combo = p >> 6;                // 0..11
    int bc = p & 63;
    int g = combo & 3;
    int dc = combo >> 2;               // 0: x[:,0:256], 1: hp[:,0:256], 2: hp[:,256:512]
    int t = threadIdx.x;
    int d = dc * 256 + t;

    f32x4 w1v[8], bbv[8], w2v[8];
    const float* W1p = W1 + ((size_t)g * D_ + d) * K_;
    const float* b1p = b1 + ((size_t)g * D_ + d) * K_;
    const float* W2p = W2 + ((size_t)g * D_ + d) * K_;
#pragma unroll
    for (int q = 0; q < 8; ++q) {
      w1v[q] = *(const f32x4*)(W1p + q * 4);
      bbv[q] = *(const f32x4*)(b1p + q * 4);
      w2v[q] = *(const f32x4*)(W2p + q * 4);
    }
    float bias = b2[(size_t)g * D_ + d];

    const float* src = (dc == 0) ? (x + t) : (hp + ((dc == 1) ? t : t + 256));
    int stride = (dc == 0) ? I_ : H_;
    int b0 = bc * 32;

#pragma unroll
    for (int bb8 = 0; bb8 < 32; bb8 += 8) {
      float cv[8], acc[8];
#pragma unroll
      for (int j = 0; j < 8; ++j) {
        cv[j] = src[(size_t)(b0 + bb8 + j) * stride];
        acc[j] = bias;
      }
#pragma unroll
      for (int q = 0; q < 8; ++q)
#pragma unroll
        for (int e = 0; e < 4; ++e) {
          float w1 = w1v[q][e], bbk = bbv[q][e], w2 = w2v[q][e];
#pragma unroll
          for (int j = 0; j < 8; ++j) {
            float h = fmaxf(fmaf(cv[j], w1, bbk), 0.f);
            acc[j] = fmaf(h, w2, acc[j]);
          }
        }
#pragma unroll
      for (int j = 0; j < 8; ++j)
        uT[((size_t)g * B_ + b0 + bb8 + j) * D_ + d] = f2bf(acc[j]);
    }
  }
}

// ---- phase 2 v7: 64(b) x 64(h) x 4 gates per block, 16 waves (1024 thr),
//      256 blocks (full chip), NBUF=4 counted-vmcnt global_load_lds pipeline,
//      staged bytes 192MB with natural per-XCD A-panel affinity (flat%8==bx%8),
//      fused LSTM epilogue ----
#define TBM 64
#define THN 64
#define BK2 32
#define NT2 (D_ / BK2)               // 24
#define AREG 16384                   // A region bytes per buffer
#define BUF2 32768                   // per-buffer total (A 16K + B 16K)
#define NBUF2 4

__global__ __launch_bounds__(1024, 4) void kan_phase2(
    const ushort_t* __restrict__ uT, const ushort_t* __restrict__ wcT,
    const float* __restrict__ bc, const float* __restrict__ cprev,
    float* __restrict__ out) {
  __shared__ __align__(16) char smem[NBUF2 * BUF2];   // 131072 B
  const int b0 = blockIdx.x * TBM;     // bx: 0..31 ; flat%8 = bx%8 -> A-panel/XCD affinity
  const int h0 = blockIdx.y * THN;     // by: 0..7
  const int t = threadIdx.x;
  const int w = t >> 6;
  const int l = t & 63;
  const int g = w >> 2, mh = w & 3;    // wave = (gate, b-quarter)
  const int frow = l & 15, c0 = l >> 4;

  // ---- staging: thread t stages A-slot t and B-slot t (16B each) ----
  // slot t: row = t>>2 (= gg*64 + r), chunk c = t&3; LDS linear, global pre-swizzled
  const int srow = t >> 2, sc = t & 3;
  const int sg = srow >> 6, sr = srow & 63;
  const int scg = sc ^ ((sr ^ (sr >> 2)) & 3);
  const ushort_t* asrc = uT + ((size_t)sg * B_ + b0 + sr) * D_ + scg * 8;
  const ushort_t* bsrc = wcT + ((size_t)sg * H_ + h0 + sr) * D_ + scg * 8;
  const int aLds = t * 16;
  const int bLds = AREG + t * 16;

  // ---- compute-side LDS offsets (read swizzle = same involution) ----
  const int key = (frow ^ (frow >> 2)) & 3;
  const int cx = ((c0 ^ key) << 4);
  const int aoff = ((g * 64 + mh * 16 + frow) << 6) + cx;
  int boff[4];
#pragma unroll
  for (int n = 0; n < 4; ++n)
    boff[n] = AREG + ((g * 64 + n * 16 + frow) << 6) + cx;

  // ---- accumulators, bias folded in (C col = lane&15) ----
  f32x4 acc[4];
#pragma unroll
  for (int n = 0; n < 4; ++n) {
    float bv = bc[(size_t)g * H_ + h0 + n * 16 + frow];
    acc[n] = (f32x4){bv, bv, bv, bv};
  }

  auto stage = [&](int bufoff, int ke) {
    gload16(asrc + ke, smem + bufoff + aLds);
    gload16(bsrc + ke, smem + bufoff + bLds);
  };
  auto compute = [&](const char* bb) {
    bf16x8 af = *(const bf16x8*)(bb + aoff);
    bf16x8 bf[4];
#pragma unroll
    for (int n = 0; n < 4; ++n) bf[n] = *(const bf16x8*)(bb + boff[n]);
    __builtin_amdgcn_s_setprio(1);
#pragma unroll
    for (int n = 0; n < 4; ++n)
      acc[n] = __builtin_amdgcn_mfma_f32_16x16x32_bf16(af, bf[n], acc[n], 0, 0, 0);
    __builtin_amdgcn_s_setprio(0);
  };

  // ---- prologue: 3 K-tiles in flight ----
  stage(0 * BUF2, 0 * BK2);
  stage(1 * BUF2, 1 * BK2);
  stage(2 * BUF2, 2 * BK2);
  int s = 0;
  for (; s < NT2 - 3; ++s) {           // steady state: 2 newer stages (4 loads) in flight
    asm volatile("s_waitcnt vmcnt(4)" ::: "memory");
    __builtin_amdgcn_s_barrier();
    stage(((s + 3) & 3) * BUF2, (s + 3) * BK2);
    compute(smem + (s & 3) * BUF2);
  }
  asm volatile("s_waitcnt vmcnt(4)" ::: "memory");   // s = NT2-3
  __builtin_amdgcn_s_barrier();
  compute(smem + (s & 3) * BUF2);
  ++s;
  asm volatile("s_waitcnt vmcnt(2)" ::: "memory");   // s = NT2-2
  __builtin_amdgcn_s_barrier();
  compute(smem + (s & 3) * BUF2);
  ++s;
  asm volatile("s_waitcnt vmcnt(0)" ::: "memory");   // s = NT2-1
  __builtin_amdgcn_s_barrier();
  compute(smem + (s & 3) * BUF2);
  __syncthreads();                     // all MFMA reads done before gf overlay

  // ---- epilogue: gate tiles gf [4][64][68] f32 (70KB), fused LSTM ----
  float* gf = (float*)smem;
#pragma unroll
  for (int n = 0; n < 4; ++n)
#pragma unroll
    for (int e = 0; e < 4; ++e) {
      int row = mh * 16 + c0 * 4 + e;
      int col = n * 16 + frow;
      gf[((size_t)g * 64 + row) * 68 + col] = acc[n][e];
    }
  __syncthreads();

  {
    int row = t >> 4;                  // 0..63
    int ch = t & 15;                   // h-chunk of 4
    int b = b0 + row;
    int hc = h0 + ch * 4;
    f32x4 g0 = *(const f32x4*)&gf[((size_t)0 * 64 + row) * 68 + ch * 4];
    f32x4 g1 = *(const f32x4*)&gf[((size_t)1 * 64 + row) * 68 + ch * 4];
    f32x4 g2 = *(const f32x4*)&gf[((size_t)2 * 64 + row) * 68 + ch * 4];
    f32x4 g3 = *(const f32x4*)&gf[((size_t)3 * 64 + row) * 68 + ch * 4];
    f32x4 cp = *(const f32x4*)&cprev[(size_t)b * H_ + hc];
    f32x4 hv, cv;
#pragma unroll
    for (int e = 0; e < 4; ++e) {
      float ft = fast_sigmoid(g0[e]);
      float it = fast_sigmoid(g1[e]);
      float ot = fast_sigmoid(g2[e]);
      float tc = fast_tanh(g3[e]);
      float cn = ft * cp[e] + it * tc;
      cv[e] = cn;
      hv[e] = ot * fast_tanh(cn);
    }
    *(f32x4*)&out[(size_t)b * H_ + hc] = hv;
    *(f32x4*)&out[(size_t)B_ * H_ + (size_t)b * H_ + hc] = cv;
  }
}

extern "C" void kernel_launch(void* const* d_in, const int* in_sizes, int n_in,
                              void* d_out, int out_size, void* d_ws, size_t ws_size,
                              hipStream_t stream) {
  const float* x  = (const float*)d_in[0];
  const float* hp = (const float*)d_in[1];
  const float* cp = (const float*)d_in[2];
  const float* W1 = (const float*)d_in[3];
  const float* b1 = (const float*)d_in[4];
  const float* W2 = (const float*)d_in[5];
  const float* b2 = (const float*)d_in[6];
  const float* Wc = (const float*)d_in[7];
  const float* bc = (const float*)d_in[8];
  float* out = (float*)d_out;

  // workspace layout
  ushort_t* wcT = (ushort_t*)d_ws;                  // 4*512*768 bf16
  ushort_t* uT  = wcT + (size_t)4 * H_ * D_;        // 4*2048*768 bf16

  kan_prep<<<2304, 256, 0, stream>>>(x, hp, W1, b1, W2, b2, Wc, wcT, uT);
  kan_phase2<<<dim3(B_ / TBM, H_ / THN), 1024, 0, stream>>>(uT, wcT, bc, cp, out);
}